// Round 12
// baseline (98.257 us; speedup 1.0000x reference)
//
#include <hip/hip_runtime.h>

// Predictive-coding graph message passing, MI355X — round 22.
// R21 = 97.8us. Ledger: S~78us structural (256MiB poison fill 41.5us at
// ~81% HBM peak + harness reset dispatches + 4 launch boundaries) and
// K~19-20us kernels vs ~14-16us latency floor. Dispatch depth 4 is minimal
// (hist->scatter->pass1->pass2 true global deps; in-kernel barriers
// measured 3-10x worse, R15/R16). R22 = final issue-count polish:
//  (1) scatter preamble uint4: 4 buckets/thread x 8 rows -> 8 VMEM instrs
//      (was 32); qpre/qtot -> [16][256] (75KB LDS, still fine).
//  (2) cntL row read uint4 (tid<64).
//  (3) k_pass: cross-wave prefix + 16-elem scan fused into wave 0 via
//      __shfl_up -> one fewer barrier per tile.
// Pre-committed: if gain < 1.5us, declare structural roofline.

static constexpr int kB = 32, kLogB = 5;
static constexpr int kBkt = 256;        // coarse buckets (16 nodes each)
static constexpr int kNPB = 16;         // nodes per bucket
static constexpr int kChunk = 4096;     // edges per chunk block
static constexpr int kTile = 2560;      // pass LDS tile (mean 2048, +11sigma)

// ---- K1: per-chunk dual histograms + fused transpose/tanh. --------------
__global__ void __launch_bounds__(1024) k_hist(
    const int* __restrict__ esrc, const int* __restrict__ edst,
    const float* __restrict__ x, float* __restrict__ x_t,
    float* __restrict__ fx_t, unsigned* __restrict__ cntA,
    unsigned* __restrict__ cntB, int N, int E, int nBB) {
  __shared__ unsigned hA[kBkt], hB[kBkt];
  __shared__ float tile[32][65];
  int tid = threadIdx.x, blk = blockIdx.x;
  if (blk < nBB) {
    if (tid < kBkt) { hA[tid] = 0u; hB[tid] = 0u; }
    __syncthreads();
    int e0 = blk * kChunk;
    if (e0 + kChunk <= E) {              // full chunk: int4 fast path
      const int4* s4 = reinterpret_cast<const int4*>(esrc + e0);
      const int4* d4 = reinterpret_cast<const int4*>(edst + e0);
      int4 sv = s4[tid], dv = d4[tid];   // kChunk/4 == 1024 == blockDim
      atomicAdd(&hA[((unsigned)dv.x) >> 4], 1u);
      atomicAdd(&hA[((unsigned)dv.y) >> 4], 1u);
      atomicAdd(&hA[((unsigned)dv.z) >> 4], 1u);
      atomicAdd(&hA[((unsigned)dv.w) >> 4], 1u);
      atomicAdd(&hB[((unsigned)sv.x) >> 4], 1u);
      atomicAdd(&hB[((unsigned)sv.y) >> 4], 1u);
      atomicAdd(&hB[((unsigned)sv.z) >> 4], 1u);
      atomicAdd(&hB[((unsigned)sv.w) >> 4], 1u);
    } else {                             // tail chunk: scalar
      int len = E - e0;
      for (int i = tid; i < len; i += 1024) {
        atomicAdd(&hA[((unsigned)edst[e0 + i]) >> 4], 1u);
        atomicAdd(&hB[((unsigned)esrc[e0 + i]) >> 4], 1u);
      }
    }
    __syncthreads();
    if (tid < kBkt) {                    // non-atomic coalesced row write
      cntA[(size_t)blk * kBkt + tid] = hA[tid];
      cntB[(size_t)blk * kBkt + tid] = hB[tid];
    }
  } else if (blk - nBB < (N >> 6)) {
    int n0 = (blk - nBB) * 64;
    for (int k = tid; k < 32 * 64; k += 1024) {  // coalesced 256B rows
      int b = k >> 6, n = k & 63;
      tile[b][n] = x[b * N + n0 + n];
    }
    __syncthreads();
    for (int k = tid; k < 64 * 32; k += 1024) {  // coalesced t-layout
      int n = k >> 5, b = k & 31;
      float xv = tile[b][n];
      int j = (n0 + n) * kB + b;
      x_t[j] = xv;
      fx_t[j] = tanhf(xv);
    }
  }
}

// ---- K2: self-scanning deterministic scatter. 256 blocks (1/CU), one
// (direction, chunk) each. Preamble: uint4 read of the L2-resident
// [128][256] cnt matrix (thread = 4 buckets x 8 rows) -> per-bucket
// {prefix-below-c, total}; single-wave shfl scan gives global bases. ----
__global__ void __launch_bounds__(1024) k_scatter(
    const int* __restrict__ esrc, const int* __restrict__ edst,
    const float* __restrict__ wgt,
    const unsigned* __restrict__ cntA, const unsigned* __restrict__ cntB,
    uint2* __restrict__ recA, uint2* __restrict__ recB,
    unsigned* __restrict__ segA, unsigned* __restrict__ segB,
    int E, int nBB) {
  __shared__ unsigned qpre[16][kBkt], qtot[16][kBkt];   // 32 KB
  __shared__ unsigned colPre[kBkt], colTot[kBkt], segL[kBkt];
  __shared__ unsigned myBase[kBkt], cntL[kBkt], baseL[kBkt], cnt2[kBkt];
  __shared__ uint2 cmp[kChunk];          // 32 KB chunk-sorted records
  __shared__ unsigned char bktid[kChunk];
  int tid = threadIdx.x, blk = blockIdx.x;
  int dir = (blk >= nBB);
  int c = blk - (dir ? nBB : 0);
  const unsigned* cnt = dir ? cntB : cntA;
  uint2* out = dir ? recB : recA;

  // Preamble: thread (q = tid>>6, g = tid&63) owns buckets 4g..4g+3 over
  // rows q*8..q*8+7. uint4 loads: row stride 1KB, col offset 16B-aligned.
  {
    int g = tid & 63, q = tid >> 6;
    int rbeg = q * 8;
    unsigned p0 = 0, p1 = 0, p2 = 0, p3 = 0;
    unsigned t0 = 0, t1 = 0, t2 = 0, t3 = 0;
#pragma unroll
    for (int u = 0; u < 8; ++u) {        // 8 uint4 loads in flight
      int row = rbeg + u;
      uint4 cc = (row < nBB)
          ? reinterpret_cast<const uint4*>(cnt + (size_t)row * kBkt)[g]
          : make_uint4(0u, 0u, 0u, 0u);
      t0 += cc.x; t1 += cc.y; t2 += cc.z; t3 += cc.w;
      if (row < c) { p0 += cc.x; p1 += cc.y; p2 += cc.z; p3 += cc.w; }
    }
    int b4 = g << 2;
    qpre[q][b4] = p0; qpre[q][b4 + 1] = p1;
    qpre[q][b4 + 2] = p2; qpre[q][b4 + 3] = p3;
    qtot[q][b4] = t0; qtot[q][b4 + 1] = t1;
    qtot[q][b4 + 2] = t2; qtot[q][b4 + 3] = t3;
  }
  __syncthreads();
  if (tid < kBkt) {
    unsigned sp = 0, st = 0;
#pragma unroll
    for (int q = 0; q < 16; ++q) { sp += qpre[q][tid]; st += qtot[q][tid]; }
    colPre[tid] = sp;
    colTot[tid] = st;
  }
  __syncthreads();
  if (tid < 64) {                        // single-wave excl scan of totals
    int qq = tid << 2;
    unsigned c0 = colTot[qq], c1 = colTot[qq + 1];
    unsigned c2 = colTot[qq + 2], c3 = colTot[qq + 3];
    unsigned s = c0 + c1 + c2 + c3, run = s;
#pragma unroll
    for (int o = 1; o < 64; o <<= 1) {
      unsigned v = __shfl_up(run, o, 64);
      if (tid >= o) run += v;
    }
    unsigned bse = run - s;
    segL[qq] = bse; segL[qq + 1] = bse + c0;
    segL[qq + 2] = bse + c0 + c1; segL[qq + 3] = bse + c0 + c1 + c2;
  }
  __syncthreads();
  if (c == 0 && tid < kBkt) {            // publish segment bounds for k_pass
    unsigned* seg = dir ? segB : segA;
    seg[tid] = segL[tid];
    if (tid == kBkt - 1) seg[kBkt] = segL[tid] + colTot[tid];
  }
  if (tid < kBkt) {
    myBase[tid] = segL[tid] + colPre[tid];   // this chunk's global run base
    cnt2[tid] = 0u;
  }
  if (tid < 64) {                        // uint4 row read of this chunk
    uint4 cc = reinterpret_cast<const uint4*>(cnt + (size_t)c * kBkt)[tid];
    int b4 = tid << 2;
    cntL[b4] = cc.x; cntL[b4 + 1] = cc.y;
    cntL[b4 + 2] = cc.z; cntL[b4 + 3] = cc.w;
  }
  __syncthreads();
  if (tid < 64) {                        // local excl scan of this chunk
    int qq = tid << 2;
    unsigned c0 = cntL[qq], c1 = cntL[qq + 1];
    unsigned c2 = cntL[qq + 2], c3 = cntL[qq + 3];
    unsigned s = c0 + c1 + c2 + c3, run = s;
#pragma unroll
    for (int o = 1; o < 64; o <<= 1) {
      unsigned v = __shfl_up(run, o, 64);
      if (tid >= o) run += v;
    }
    unsigned bse = run - s;
    baseL[qq] = bse; baseL[qq + 1] = bse + c0;
    baseL[qq + 2] = bse + c0 + c1; baseL[qq + 3] = bse + c0 + c1 + c2;
  }
  __syncthreads();
  int e0 = c * kChunk;
  const int* key = dir ? esrc : edst;    // A: by dst, B: by src
  const int* oth = dir ? edst : esrc;
#define SC_PUT(KY, OT, WT)                                           \
  { unsigned ky = (unsigned)(KY), ot = (unsigned)(OT);               \
    unsigned bbk = ky >> 4;                                          \
    unsigned slot = baseL[bbk] + atomicAdd(&cnt2[bbk], 1u);          \
    cmp[slot] = make_uint2((ot << 4) | (ky & 15u),                   \
                           __float_as_uint(WT));                     \
    bktid[slot] = (unsigned char)bbk; }
  int len;
  if (e0 + kChunk <= E) {                // full chunk: int4/float4 fast path
    len = kChunk;
    const int4* k4 = reinterpret_cast<const int4*>(key + e0);
    const int4* o4 = reinterpret_cast<const int4*>(oth + e0);
    const float4* w4 = reinterpret_cast<const float4*>(wgt + e0);
    int4 kv = k4[tid]; int4 ov = o4[tid]; float4 wv = w4[tid];
    SC_PUT(kv.x, ov.x, wv.x)
    SC_PUT(kv.y, ov.y, wv.y)
    SC_PUT(kv.z, ov.z, wv.z)
    SC_PUT(kv.w, ov.w, wv.w)
  } else {                               // tail chunk: scalar
    len = E - e0;
    for (int i = tid; i < len; i += 1024)
      SC_PUT(key[e0 + i], oth[e0 + i], wgt[e0 + i])
  }
#undef SC_PUT
  __syncthreads();
  for (int s = tid; s < len; s += 1024) {          // coalesced run copy-out
    unsigned bbk = bktid[s];
    out[myBase[bbk] + ((unsigned)s - baseL[bbk])] = cmp[s];
  }
}

// ---- K3/K4: per-bucket fine sort + select-free pipelined accumulation. --
// Records staged to LDS once; loads unconditional with clamped index; only
// the WEIGHT predicated. Prefix + scan fused into wave 0 (one barrier saved).
__global__ void __launch_bounds__(1024) k_pass(
    const uint2* __restrict__ rec, const unsigned* __restrict__ seg,
    const float* __restrict__ vals, const float* __restrict__ x_t,
    const float* __restrict__ fx_t, float* __restrict__ eps_t,
    float* __restrict__ out, int N, int mode) {
  __shared__ uint2 stg[kTile];           // 20 KB staged records
  __shared__ uint2 srt[kTile];           // 20 KB node-sorted records
  __shared__ unsigned hW[16 * kNPB];     // per-wave private hist
  __shared__ unsigned wbase[16 * kNPB];  // absolute slot base per (wave,node)
  __shared__ unsigned wcur[16 * kNPB];
  __shared__ unsigned h[kNPB], hb[kNPB];
  __shared__ float red[1024];
  int tid = threadIdx.x, t = blockIdx.x;
  int segb = (int)seg[t], sege = (int)seg[t + 1];
  int wv = tid >> 6;
  int b = tid & 31, hw = tid >> 5, l = hw >> 1, part = hw & 1;
  float acc = 0.0f;

  for (int t0 = segb; t0 < sege; t0 += kTile) {    // 1 tile except 11-sigma tail
    int len = min(kTile, sege - t0);
    if (tid < 16 * kNPB) { hW[tid] = 0u; wcur[tid] = 0u; }
    __syncthreads();
    for (int i = tid; i < len; i += 1024) {        // stage + privatized hist
      uint2 r = rec[t0 + i];
      stg[i] = r;
      atomicAdd(&hW[wv * kNPB + (r.x & 15u)], 1u);
    }
    __syncthreads();
    if (tid < kNPB) {                    // wave 0: cross-wave prefix + scan
      unsigned run = 0;
#pragma unroll
      for (int w2 = 0; w2 < 16; ++w2) {
        unsigned c = hW[w2 * kNPB + tid];
        wbase[w2 * kNPB + tid] = run;
        run += c;
      }
      h[tid] = run;
      unsigned sc = run;                 // intra-wave inclusive scan (16 lanes)
#pragma unroll
      for (int o = 1; o < kNPB; o <<= 1) {
        unsigned v = __shfl_up(sc, o, 64);
        if (tid >= o) sc += v;
      }
      hb[tid] = sc - run;                // exclusive base
    }
    __syncthreads();
    if (tid < 16 * kNPB) wbase[tid] += hb[tid & (kNPB - 1)];
    __syncthreads();
    for (int i = tid; i < len; i += 1024) {        // fine sort (LDS -> LDS)
      uint2 r = stg[i];
      unsigned lx = r.x & 15u;
      srt[wbase[wv * kNPB + lx] + atomicAdd(&wcur[wv * kNPB + lx], 1u)] = r;
    }
    __syncthreads();

    int beg = (int)hb[l] + part, end = (int)hb[l] + (int)h[l];
    int last = end - 1; if (last < 0) last = 0;
    uint2 r0, r1, r2, r3, r4, r5, r6, r7;
    float v0, v1, v2, v3, v4, v5, v6, v7;
#define PC_LOAD(d)                                                   \
    { int p = beg + 2 * (d); uint2 rr = srt[min(p, last)];           \
      r##d = rr; v##d = vals[(((rr.x >> 4) & 4095u) << kLogB) + b]; }
    PC_LOAD(0) PC_LOAD(1) PC_LOAD(2) PC_LOAD(3)
    PC_LOAD(4) PC_LOAD(5) PC_LOAD(6) PC_LOAD(7)
#undef PC_LOAD
    int i = beg;
    while (i < end) {
#define PC_STEP(d)                                                   \
      { float wt = (i + 2 * (d) < end) ? __uint_as_float(r##d.y) : 0.0f; \
        acc = fmaf(wt, v##d, acc);                                   \
        int p = i + 16 + 2 * (d); uint2 rr = srt[min(p, last)];      \
        r##d = rr; v##d = vals[(((rr.x >> 4) & 4095u) << kLogB) + b]; }
      PC_STEP(0) PC_STEP(1) PC_STEP(2) PC_STEP(3)
      PC_STEP(4) PC_STEP(5) PC_STEP(6) PC_STEP(7)
#undef PC_STEP
      i += 16;
    }
    __syncthreads();                               // srt/hW reused next tile
  }

  red[tid] = acc;
  __syncthreads();
  if (part == 0) {                                 // combine 2 parts, write
    float s = red[tid] + red[tid + 32];
    int n = t * kNPB + l;
    int j = (n << kLogB) + b;
    if (mode == 0) {
      out[b * N + n] = s;                          // mu: full 64B line
      eps_t[j] = x_t[j] - s;
    } else {
      float fx = fx_t[j];
      out[b * N + n] = fmaf(1.0f - fx * fx, s, -eps_t[j]);  // dx
    }
  }
}

extern "C" void kernel_launch(void* const* d_in, const int* in_sizes, int n_in,
                              void* d_out, int out_size, void* d_ws, size_t ws_size,
                              hipStream_t stream) {
  const float* x    = (const float*)d_in[0];
  const float* w    = (const float*)d_in[1];
  const int*   esrc = (const int*)d_in[2];
  const int*   edst = (const int*)d_in[3];

  int BN = in_sizes[0];                  // 131072
  int E  = in_sizes[1];                  // 524288
  int N  = BN / kB;                      // 4096
  int nBB = (E + kChunk - 1) / kChunk;   // 128

  float* ws    = (float*)d_ws;
  float* x_t   = ws;                     // [BN]
  float* fx_t  = ws + (size_t)BN;        // [BN]
  float* eps_t = ws + 2 * (size_t)BN;    // [BN]
  unsigned* cntA = (unsigned*)(ws + 3 * (size_t)BN);    // [nBB*256] 128 KB
  unsigned* cntB = cntA + (size_t)nBB * kBkt;
  unsigned* segA = cntB + (size_t)nBB * kBkt;           // [257] (512 pad)
  unsigned* segB = segA + 512;
  uint2* recA = (uint2*)(segB + 512);                   // [E] 4 MB dense
  uint2* recB = recA + (size_t)E;                       // [E] 4 MB dense

  float* out_mu = (float*)d_out;
  float* out_dx = (float*)d_out + BN;

  k_hist<<<nBB + (N >> 6), 1024, 0, stream>>>(esrc, edst, x, x_t, fx_t,
                                              cntA, cntB, N, E, nBB);
  k_scatter<<<2 * nBB, 1024, 0, stream>>>(esrc, edst, w, cntA, cntB,
                                          recA, recB, segA, segB, E, nBB);
  // Pass 1: mu[n] = sum_{e: dst=n} w_e * fx[src_e]; eps = x - mu.
  k_pass<<<kBkt, 1024, 0, stream>>>(recA, segA, fx_t, x_t, fx_t,
                                    eps_t, out_mu, N, 0);
  // Pass 2: dx[n] = -eps[n] + f'(x_n) * sum_{e: src=n} w_e * eps[dst_e].
  k_pass<<<kBkt, 1024, 0, stream>>>(recB, segB, eps_t, x_t, fx_t,
                                    eps_t, out_dx, N, 1);
}